// Round 21
// baseline (46.456 us; speedup 1.0000x reference)
//
#include <hip/hip_runtime.h>

// Problem constants: B=8, H=320, W=1024, CH=CW=3, MAXINS=200
#define BATCH   8
#define HW      (320 * 1024)        // 327680 pixels per batch (mult of 4)
#define ELEMS   (HW * 9)            // 2949120 floats per batch
#define NQUADS  (HW / 4)            // 81920 pixel-quads per batch
#define MAXINS  200
#define BINS    (MAXINS * 9)        // 1800 bins; stride 9: gcd(9,32)=1
#define NXBLK   32                  // compress x-blocks/batch (R20: 1 blk/CU)
#define CBLK    512                 // 8 waves/block
#define QPT     5                   // quads/thread: 32*512*5 = 81920 = NQUADS
#define IXBLK   128                 // inflate x-blocks/batch (was 512):
                                    // 1024 blocks -> table staging instances
                                    // /4 (29.5 -> 7.4 MB + converts /4) —
                                    // same per-instance fixed-cost mechanism
                                    // as R19/R20, applied to inflate
#define SCALE      2097152.0f       // 2^21 fixed-point scale
#define INV_SCALE_D (1.1 / 2097152.0)

// Decode an 8-element group starting at e (inflate path): spans <=2 pixels.
__device__ __forceinline__ void decode8(int e, int& pix0, int& pix1,
                                        int& j0, int& b) {
    pix0 = e / 9;
    j0   = e - pix0 * 9;
    b    = 9 - j0;
    pix1 = (e + 7) / 9;
}

// ---------------------------------------------------------------------------
// Compress (R20 config — frozen): 256 histogram instances, 1 block/CU.
// Confirmed mechanism: per-instance fixed cost (R13 +11us/1280, R19 -2.7us/
// -640, R20 -1.9us/-384). Exhausted: can't go below 1 block/CU.
// Null mechanisms (do not revisit): more blocks (R13), more waves (R14),
// coalesced loads (R15), dual histograms (R16), stride-12 LDS (R10).
// ---------------------------------------------------------------------------
__global__ __launch_bounds__(CBLK) void epp_compress(
    const int* __restrict__ inst, const float* __restrict__ src,
    int* __restrict__ compi)
{
    __shared__ int bins[BINS];
    const int b = blockIdx.y;

    for (int i = threadIdx.x; i < BINS; i += CBLK) bins[i] = 0;
    __syncthreads();

    const int* __restrict__ instb = inst + b * HW;
    const float4* __restrict__ srcb = (const float4*)(src + (size_t)b * ELEMS);
    const int qbase = blockIdx.x * (CBLK * QPT) + threadIdx.x;

#pragma unroll 1
    for (int it = 0; it < QPT; ++it) {
        const int q = qbase + it * CBLK;             // max 81919 < NQUADS
        const int p = q * 4;                         // first pixel (4-aligned)
        const int4 ids = *(const int4*)(instb + p);  // 16B-aligned id load
        int base[4] = {ids.x * 9, ids.y * 9, ids.z * 9, ids.w * 9};

        const float4* s = srcb + (size_t)q * 9;      // 36 floats, 16B-aligned
        float4 f[9];
#pragma unroll
        for (int r = 0; r < 9; ++r) f[r] = s[r];

#pragma unroll
        for (int r = 0; r < 9; ++r) {
            const float v[4] = {f[r].x, f[r].y, f[r].z, f[r].w};
#pragma unroll
            for (int c = 0; c < 4; ++c) {
                const int i  = 4 * r + c;            // 0..35, static
                const int px = i / 9;                // static
                const int j  = i - px * 9;           // static
                atomicAdd(&bins[base[px] + j],       // ds_add, imm offset j
                          __float2int_rn(v[c] * SCALE));
            }
        }
    }
    __syncthreads();

    // Identity flush: native global int atomics into the per-batch table.
    int* __restrict__ cb = compi + b * BINS;
    for (int i = threadIdx.x; i < BINS; i += CBLK) {
        atomicAdd(&cb[i], bins[i]);
    }
}

// ---------------------------------------------------------------------------
// Inflate: same gather/store body, but 1024 blocks instead of 4096 — the
// 7.2KB table staging + 1800 converts are per-BLOCK fixed cost (the R11
// "at roofline" verdict came from a 4-pass diagnostic that amortized this).
// ---------------------------------------------------------------------------
__global__ __launch_bounds__(256) void epp_inflate(
    const int* __restrict__ inst, const int* __restrict__ compi,
    float* __restrict__ out)
{
    __shared__ float bins[BINS];
    const int b = blockIdx.y;
    const int* __restrict__ cb = compi + b * BINS;
    for (int i = threadIdx.x; i < BINS; i += 256) {
        bins[i] = (float)((double)cb[i] * INV_SCALE_D);
    }
    __syncthreads();

    const int total8 = ELEMS / 8;
    const int* __restrict__ instb = inst + b * HW;
    float4* __restrict__ outb = (float4*)(out + (size_t)b * ELEMS);
    const int stride = gridDim.x * 256;

    for (int g = blockIdx.x * 256 + threadIdx.x; g < total8; g += stride) {
        const int e = g * 8;
        int pix0, pix1, j0, cnt8;
        decode8(e, pix0, pix1, j0, cnt8);
        const int id0 = instb[pix0] * 9 + j0;
        const int id1 = instb[pix1] * 9 + j0 - 9;
        float vals[8];
#pragma unroll
        for (int k = 0; k < 8; ++k) {
            int base = (k < cnt8) ? id0 : id1;
            vals[k] = bins[base + k];
        }
        outb[2 * g]     = make_float4(vals[0], vals[1], vals[2], vals[3]);
        outb[2 * g + 1] = make_float4(vals[4], vals[5], vals[6], vals[7]);
    }
}

extern "C" void kernel_launch(void* const* d_in, const int* in_sizes, int n_in,
                              void* d_out, int out_size, void* d_ws, size_t ws_size,
                              hipStream_t stream) {
    const int*   inst = (const int*)d_in[0];    // [B,1,H,W] int32
    const float* src  = (const float*)d_in[1];  // [B,H,W,3,3] f32
    float* out = (float*)d_out;                 // [B,H,W,3,3] f32

    const size_t compBytes = (size_t)BATCH * BINS * sizeof(int);   // 57.6 KB
    if (ws_size < compBytes) return;            // ws has always been >= 300MB

    int* compi = (int*)d_ws;

    // Zero the int accumulator every call (graph-safe, 57.6 KB).
    (void)hipMemsetAsync(compi, 0, compBytes, stream);

    dim3 cgrid(NXBLK, BATCH);                   // 256 blocks x 512 threads
    epp_compress<<<cgrid, CBLK, 0, stream>>>(inst, src, compi);

    dim3 igrid(IXBLK, BATCH);                   // 1024 blocks x 256 threads
    epp_inflate<<<igrid, 256, 0, stream>>>(inst, compi, out);
}